// Round 10
// baseline (1891.502 us; speedup 1.0000x reference)
//
#include <hip/hip_runtime.h>
#include <hip/hip_bf16.h>
#include <math.h>

// Problem constants
#define B_ 8
#define S_ 32
#define J_ 4
#define L_ 32
#define E_ 500
#define H_ 500
#define NI_ 5000
#define NT_ 48
#define G4_ 2000   // 4*H

#define PZH_ 2.0f    // poison for h-valued buffers: |h| <= 1 always, never 2.0
#define PZC_ 1e30f   // poison for cell buffer: |c| <= steps+1 <= 129, never 1e30

typedef unsigned long long ull;

__device__ __forceinline__ float sigm(float x) { return 1.f / (1.f + expf(-x)); }
__device__ __forceinline__ float seluf(float x) {
    const float sc = 1.0507009873554805f, al = 1.6732632423543772f;
    return x > 0.f ? sc * x : sc * al * (expf(x) - 1.f);
}
// agent-scope ops: bypass L1/L2, coherent at L3; no fences / no wbl2
__device__ __forceinline__ float cohload(const float* p) {
    return __hip_atomic_load(p, __ATOMIC_RELAXED, __HIP_MEMORY_SCOPE_AGENT);
}
__device__ __forceinline__ ull cohload64(const ull* p) {
    return __hip_atomic_load(p, __ATOMIC_RELAXED, __HIP_MEMORY_SCOPE_AGENT);
}
__device__ __forceinline__ void cohstore(float* p, float v) {
    __hip_atomic_store(p, v, __ATOMIC_RELAXED, __HIP_MEMORY_SCOPE_AGENT);
}

// ---------------- poison the exchange buffers (every launch) ----------------
__global__ __launch_bounds__(256) void k_poison(float* __restrict__ outm,
                                                float* __restrict__ outh,
                                                float* __restrict__ csg,
                                                float* __restrict__ he) {
    int i = blockIdx.x * 256 + threadIdx.x;
    if (i < 128000) { outm[i] = PZH_; outh[i] = PZH_; csg[i] = PZC_; }
    if (i < 512000) he[i] = PZH_;
}

// ---------------- embedding gather ----------------
__global__ __launch_bounds__(128) void k_embed(const int* __restrict__ itemv,
                                               const int* __restrict__ histi,
                                               const float* __restrict__ embW,
                                               float* __restrict__ items,
                                               float* __restrict__ histemb) {
    int row = blockIdx.x;
    int id;
    float* dst;
    if (row < 256) { id = itemv[row]; dst = items + (size_t)row * E_; }
    else           { int rr = row - 256; id = histi[rr]; dst = histemb + (size_t)rr * E_; }
    const float4* s = (const float4*)(embW + (size_t)id * E_);
    float4* d = (float4*)dst;
    if (threadIdx.x < 125) d[threadIdx.x] = s[threadIdx.x];
}

// ---------------- generic GEMM: C[M,N] = A[M,K] @ B[N,K]^T + bias[N] ----------------
#define TBM 64
#define TBN 64
#define TBK 16
__global__ __launch_bounds__(256) void k_gemm_bt(const float* __restrict__ A,
                                                 const float* __restrict__ Bm,
                                                 const float* __restrict__ bias,
                                                 float* __restrict__ C,
                                                 int M, int N, int K) {
    __shared__ float As[TBK][TBM + 1];
    __shared__ float Bs[TBK][TBN + 1];
    const int tid = threadIdx.x;
    const int tx = tid & 15, ty = tid >> 4;
    const int row0 = blockIdx.y * TBM, col0 = blockIdx.x * TBN;
    float acc[4][4] = {};
    for (int k0 = 0; k0 < K; k0 += TBK) {
#pragma unroll
        for (int i = 0; i < 4; ++i) {
            int e = tid + i * 256;
            int kk = e & 15, m = e >> 4;
            int gk = k0 + kk;
            float va = 0.f, vb = 0.f;
            int gm = row0 + m, gn = col0 + m;
            if (gk < K) {
                if (gm < M) va = A[(size_t)gm * K + gk];
                if (gn < N) vb = Bm[(size_t)gn * K + gk];
            }
            As[kk][m] = va;
            Bs[kk][m] = vb;
        }
        __syncthreads();
#pragma unroll
        for (int kk = 0; kk < TBK; ++kk) {
            float a[4], bb[4];
#pragma unroll
            for (int i = 0; i < 4; ++i) a[i] = As[kk][ty * 4 + i];
#pragma unroll
            for (int i = 0; i < 4; ++i) bb[i] = Bs[kk][tx * 4 + i];
#pragma unroll
            for (int i = 0; i < 4; ++i)
#pragma unroll
                for (int j = 0; j < 4; ++j) acc[i][j] += a[i] * bb[j];
        }
        __syncthreads();
    }
#pragma unroll
    for (int i = 0; i < 4; ++i) {
        int gm = row0 + ty * 4 + i;
        if (gm >= M) continue;
#pragma unroll
        for (int j = 0; j < 4; ++j) {
            int gn = col0 + tx * 4 + j;
            if (gn < N) C[(size_t)gm * N + gn] = acc[i][j] + (bias ? bias[gn] : 0.f);
        }
    }
}

// ---------------- per-batch gang recurrent kernel (v10: poll-on-data) ----------------
// Same geometry as v9 (24 independent per-(role,batch) gangs, 256 blocks).
// NO flags, NO gang barrier: consumers poll the exchanged data itself.
// Buffers are pre-poisoned (k_poison) with values the LSTM can never emit
// (h-buffers: 2.0; cell buffer: 1e30). A staging thread spins on its own
// 16B chunk until all 4 floats != poison, then writes LDS. Sync chain per
// step = producer store-visible (~1 RT) + consumer poll-read (~1 RT),
// replacing the 4-RT flag protocol. Per-4B-word tearing impossible (each
// word single-written). Poison kernel re-runs every launch (replay-safe).
__global__ __launch_bounds__(256) void k_rec10(
    const float* __restrict__ xwm, const float* __restrict__ Whm,
    const float* __restrict__ xwd, const float* __restrict__ Whd,
    const int* __restrict__ dilidx,
    const float* __restrict__ xwh, const float* __restrict__ Whh,
    float* __restrict__ outm, float* __restrict__ outh,
    float* __restrict__ csg, float* __restrict__ he) {
    __shared__ __align__(16) float4 h_s4[125];
    __shared__ float z_s[256];
    const int tid = threadIdx.x;
    const int bid = blockIdx.x;
    const int x = bid & 7, ii = bid >> 3;   // x ~ XCD slot (perf heuristic only)
    int role, b, blk;
    if (x < 4)      { role = 2; b = x * 2 + (ii >> 4);       blk = ii & 15; }
    else if (x < 6) { role = 0; b = (x - 4) * 4 + (ii >> 3); blk = ii & 7;  }
    else            { role = 1; b = (x - 6) * 4 + (ii >> 3); blk = ii & 7;  }

    const int hpbb   = (role == 2) ? 32 : 63;
    const int r0     = blk * hpbb;
    const int hpb    = min(hpbb, 500 - r0);
    const int C      = 4 * hpb;
    const int nsteps = (role == 2) ? 128 : 32;

    const float* Wh = (role == 0) ? Whm : (role == 1) ? Whd : Whh;
    const float* xw = (role == 0) ? xwm : (role == 1) ? xwd : xwh;

    int colg = 0;
    if (tid < C) {
        int gate = tid / hpb;
        int ri = tid - gate * hpb;
        colg = gate * 500 + r0 + ri;
    }
    const float4* wp4 = (const float4*)(Wh + (size_t)colg * 500);

    float c_reg = 0.f;

    for (int t = 0; t < nsteps; ++t) {
        // xw prefetch (independent of h) -> issue first
        float acc = 0.f;
        if (tid < C) acc = xw[((size_t)(b * nsteps + t)) * G4_ + colg];

        float pc_r = 0.f;
        if (t > 0) {
            // ---- stage this batch's h row: poll own 16B chunk until real ----
            const float* hrow;
            if (role == 0)      hrow = outm + ((size_t)(b * S_ + (t - 1))) * H_;
            else if (role == 2) hrow = he + ((size_t)(b * 128 + (t - 1))) * H_;
            else { int it = dilidx[b * S_ + t];
                   hrow = outh + ((size_t)(b * S_ + it)) * H_; }
            if (tid < 125) {
                const ull* p = (const ull*)(hrow + tid * 4);
                union { ull u[2]; float4 f; float fs[4]; } uf;
                while (true) {
                    uf.u[0] = cohload64(p);
                    uf.u[1] = cohload64(p + 1);
                    if (uf.fs[0] != PZH_ && uf.fs[1] != PZH_ &&
                        uf.fs[2] != PZH_ && uf.fs[3] != PZH_) break;
                    __builtin_amdgcn_s_sleep(1);
                }
                h_s4[tid] = uf.f;
            }
            // role-1 prev-cell: poll csg (own h-range) until real
            if (role == 1 && tid < hpb) {
                int it = dilidx[b * S_ + t];
                const float* pp = &csg[((size_t)(b * S_ + it)) * H_ + r0 + tid];
                do { pc_r = cohload(pp); } while (pc_r == PZC_);
            }
            __syncthreads();

            // ---- GEMV: dot(h, W[colg]); h reads are LDS broadcasts ----
            if (tid < C) {
                float s0 = 0.f, s1 = 0.f, s2 = 0.f, s3 = 0.f;
#pragma unroll 2
                for (int k4 = 0; k4 < 124; k4 += 4) {
                    float4 w0 = wp4[k4],     h0 = h_s4[k4];
                    float4 w1 = wp4[k4 + 1], h1 = h_s4[k4 + 1];
                    float4 w2 = wp4[k4 + 2], h2 = h_s4[k4 + 2];
                    float4 w3 = wp4[k4 + 3], h3 = h_s4[k4 + 3];
                    s0 += w0.x * h0.x + w0.y * h0.y + w0.z * h0.z + w0.w * h0.w;
                    s1 += w1.x * h1.x + w1.y * h1.y + w1.z * h1.z + w1.w * h1.w;
                    s2 += w2.x * h2.x + w2.y * h2.y + w2.z * h2.z + w2.w * h2.w;
                    s3 += w3.x * h3.x + w3.y * h3.y + w3.z * h3.z + w3.w * h3.w;
                }
                float4 wt = wp4[124], ht = h_s4[124];
                s0 += wt.x * ht.x + wt.y * ht.y + wt.z * ht.z + wt.w * ht.w;
                acc += (s0 + s1) + (s2 + s3);
            }
        }
        z_s[tid] = acc;
        __syncthreads();

        // ---- gate update for this block's hpb h-indices ----
        if (tid < hpb) {
            float zi = z_s[tid];
            float zf = z_s[tid + hpb];
            float zg = z_s[tid + 2 * hpb];
            float zo = z_s[tid + 3 * hpb];
            float pc = (role == 1) ? pc_r : c_reg;
            float cc = sigm(zf) * pc + sigm(zi) * tanhf(zg);
            float hh = sigm(zo) * tanhf(cc);
            c_reg = cc;
            int r = r0 + tid;
            if (role == 0) {
                cohstore(&outm[((size_t)(b * S_ + t)) * H_ + r], hh);
            } else if (role == 2) {
                cohstore(&he[((size_t)(b * 128 + t)) * H_ + r], hh);
            } else {
                cohstore(&outh[((size_t)(b * S_ + t)) * H_ + r], hh);
                cohstore(&csg[((size_t)(b * S_ + t)) * H_ + r], cc);
            }
        }
        __syncthreads();   // protects z_s (and h_s) reuse next iteration
    }
}

// ---------------- masked mean pooling ----------------
__global__ __launch_bounds__(512) void k_pool(const float* __restrict__ outm,
                                              const float* __restrict__ mask,
                                              float* __restrict__ pooled) {
    int b = blockIdx.x, tid = threadIdx.x;
    if (tid >= 500) return;
    float acc = 0.f, den = 0.f;
    for (int s = 0; s < S_; ++s) {
        float mk = mask[b * S_ + s];
        acc += outm[((size_t)(b * S_ + s)) * H_ + tid] * mk;
        den += mk;
    }
    pooled[b * H_ + tid] = acc / den;
}

// ---------------- session rep: sess[b,j,s,:] and avgd[b,j,s] ----------------
__global__ __launch_bounds__(512) void k_sess(const int* __restrict__ seqtim,
                                              const int* __restrict__ itemv,
                                              const int* __restrict__ histt,
                                              const int* __restrict__ histi,
                                              const float* __restrict__ timsim,
                                              const float* __restrict__ poid,
                                              const float* __restrict__ he,
                                              float* __restrict__ sess,
                                              float* __restrict__ avgd) {
    int bi = blockIdx.x;                // B*J*31
    int s = bi % 31;
    int tmpv = bi / 31;
    int j = tmpv & 3, b = tmpv >> 2;
    __shared__ float w[L_];
    __shared__ float pd[L_];
    __shared__ float stats[1];
    int tid = threadIdx.x;
    int st = seqtim[b * S_ + s];
    if (tid < L_) {
        int ht = histt[(b * J_ + j) * L_ + tid];
        w[tid] = timsim[st * NT_ + ht];
    }
    if (tid >= 64 && tid < 64 + L_) {   // parallel poi_dist gather
        int l = tid - 64;
        int iv = itemv[b * S_ + s];
        pd[l] = poid[(size_t)iv * NI_ + histi[(b * J_ + j) * L_ + l]];
    }
    __syncthreads();
    if (tid == 64) {
        float a = 0.f;
        for (int l = 0; l < L_; ++l) a += pd[l];
        avgd[(b * J_ + j) * 31 + s] = a * (1.f / 32.f);
    }
    if (tid == 0) {
        float m = -1e30f;
        for (int l = 0; l < L_; ++l) m = fmaxf(m, w[l]);
        float sm = 0.f;
        for (int l = 0; l < L_; ++l) { float e = expf(w[l] - m); w[l] = e; sm += e; }
        stats[0] = 1.f / sm;
    }
    __syncthreads();
    if (tid < 500) {
        float inv = stats[0];
        float acc = 0.f;
        const float* hp = he + ((size_t)(b * J_ * L_ + j * L_)) * H_ + tid;
        for (int l = 0; l < L_; ++l) acc += w[l] * inv * hp[(size_t)l * H_];
        sess[((size_t)((b * J_ + j) * 31 + s)) * H_ + tid] = acc;
    }
}

// ---------------- attention 1 ----------------
__global__ __launch_bounds__(512) void k_att1(const float* __restrict__ sess,
                                              const float* __restrict__ pooled,
                                              float* __restrict__ att1) {
    int bi = blockIdx.x;   // B*31
    int s = bi % 31, b = bi / 31;
    __shared__ float vec[H_];
    __shared__ float part[512];
    int tid = threadIdx.x;
    if (tid < 500) vec[tid] = pooled[b * H_ + tid];
    __syncthreads();
    int j = tid >> 7, i = tid & 127;
    const float* sp = sess + ((size_t)((b * J_ + j) * 31 + s)) * H_;
    float acc = 0.f;
    for (int h = i; h < H_; h += 128) acc += sp[h] * vec[h];
    part[tid] = acc;
    __syncthreads();
    for (int off = 64; off > 0; off >>= 1) {
        if (i < off) part[tid] += part[tid + off];
        __syncthreads();
    }
    float d0 = part[0], d1 = part[128], d2 = part[256], d3 = part[384];
    float m = fmaxf(fmaxf(d0, d1), fmaxf(d2, d3));
    float e0 = expf(d0 - m), e1 = expf(d1 - m), e2 = expf(d2 - m), e3 = expf(d3 - m);
    float inv = 1.f / (e0 + e1 + e2 + e3);
    if (tid < 500) {
        const float* s0 = sess + ((size_t)(b * J_ * 31 + s)) * H_ + tid;
        const size_t js = (size_t)31 * H_;
        float r = e0 * inv * s0[0] + e1 * inv * s0[js] + e2 * inv * s0[2 * js] + e3 * inv * s0[3 * js];
        att1[((size_t)(b * 31 + s)) * H_ + tid] = r;
    }
}

// ---------------- attention 2 ----------------
__global__ __launch_bounds__(512) void k_att2(const float* __restrict__ sess,
                                              const float* __restrict__ outy,
                                              const float* __restrict__ outm,
                                              const float* __restrict__ avgd,
                                              float* __restrict__ X) {
    int bi = blockIdx.x;   // B*31
    int s = bi % 31, b = bi / 31;
    __shared__ float vec[H_];
    __shared__ float part[512];
    int tid = threadIdx.x;
    if (tid < 500)
        vec[tid] = 0.5f * seluf(outy[((size_t)(b * 31 + s)) * H_ + tid]) +
                   0.5f * outm[((size_t)(b * S_ + s)) * H_ + tid];
    __syncthreads();
    int j = tid >> 7, i = tid & 127;
    const float* sp = sess + ((size_t)((b * J_ + j) * 31 + s)) * H_;
    float acc = 0.f;
    for (int h = i; h < H_; h += 128) acc += sp[h] * vec[h];
    part[tid] = acc;
    __syncthreads();
    for (int off = 64; off > 0; off >>= 1) {
        if (i < off) part[tid] += part[tid + off];
        __syncthreads();
    }
    float d0 = part[0]   / avgd[(b * J_ + 0) * 31 + s];
    float d1 = part[128] / avgd[(b * J_ + 1) * 31 + s];
    float d2 = part[256] / avgd[(b * J_ + 2) * 31 + s];
    float d3 = part[384] / avgd[(b * J_ + 3) * 31 + s];
    float m = fmaxf(fmaxf(d0, d1), fmaxf(d2, d3));
    float e0 = expf(d0 - m), e1 = expf(d1 - m), e2 = expf(d2 - m), e3 = expf(d3 - m);
    float inv = 1.f / (e0 + e1 + e2 + e3);
    if (tid < 500) {
        const float* s0 = sess + ((size_t)(b * J_ * 31 + s)) * H_ + tid;
        const size_t js = (size_t)31 * H_;
        float r = e0 * inv * s0[0] + e1 * inv * s0[js] + e2 * inv * s0[2 * js] + e3 * inv * s0[3 * js];
        X[((size_t)(b * S_ + s)) * 1000 + tid] = seluf(r);
    }
}

// ---------------- mix ----------------
__global__ __launch_bounds__(512) void k_mix(const float* __restrict__ outm,
                                             const float* __restrict__ outh,
                                             float* __restrict__ X) {
    int bs = blockIdx.x;   // B*S
    int tid = threadIdx.x;
    if (tid >= 500) return;
    size_t idx = (size_t)bs * H_ + tid;
    float om = 0.5f * (seluf(outm[idx]) + seluf(outh[idx]));
    X[(size_t)bs * 1000 + 500 + tid] = om;
    if ((bs & (S_ - 1)) == S_ - 1) X[(size_t)bs * 1000 + tid] = 0.f;
}

// ---------------- in-place log_softmax over rows of 5000 ----------------
__global__ __launch_bounds__(512) void k_lsm(float* __restrict__ out) {
    int row = blockIdx.x, tid = threadIdx.x;
    float* p = out + (size_t)row * NI_;
    __shared__ float red[512];
    float m = -1e30f;
    for (int i = tid; i < NI_; i += 512) m = fmaxf(m, p[i]);
    red[tid] = m;
    __syncthreads();
    for (int off = 256; off > 0; off >>= 1) {
        if (tid < off) red[tid] = fmaxf(red[tid], red[tid + off]);
        __syncthreads();
    }
    m = red[0];
    __syncthreads();
    float sm = 0.f;
    for (int i = tid; i < NI_; i += 512) sm += expf(p[i] - m);
    red[tid] = sm;
    __syncthreads();
    for (int off = 256; off > 0; off >>= 1) {
        if (tid < off) red[tid] += red[tid + off];
        __syncthreads();
    }
    float lse = m + logf(red[0]);
    __syncthreads();
    for (int i = tid; i < NI_; i += 512) p[i] -= lse;
}

extern "C" void kernel_launch(void* const* d_in, const int* in_sizes, int n_in,
                              void* d_out, int out_size, void* d_ws, size_t ws_size,
                              hipStream_t stream) {
    const int* item_vectors = (const int*)d_in[0];
    const int* sequence_tim = (const int*)d_in[1];
    const int* dilated_idx  = (const int*)d_in[2];
    const int* hist_items   = (const int*)d_in[3];
    const int* hist_tims    = (const int*)d_in[4];
    const float* mask       = (const float*)d_in[5];
    const float* tim_sim    = (const float*)d_in[6];
    const float* poi_dist   = (const float*)d_in[7];
    const float* emb_W      = (const float*)d_in[8];
    const float* lstm_Wi    = (const float*)d_in[9];
    const float* lstm_Wh    = (const float*)d_in[10];
    const float* lstm_b     = (const float*)d_in[11];
    const float* hist_Wi    = (const float*)d_in[12];
    const float* hist_Wh    = (const float*)d_in[13];
    const float* hist_b     = (const float*)d_in[14];
    const float* dil_Wi     = (const float*)d_in[15];
    const float* dil_Wh     = (const float*)d_in[16];
    const float* dil_b      = (const float*)d_in[17];
    const float* lin1_W     = (const float*)d_in[18];
    const float* lin1_b     = (const float*)d_in[19];
    const float* lin_W      = (const float*)d_in[20];
    const float* lin_b      = (const float*)d_in[21];
    float* out = (float*)d_out;
    float* ws  = (float*)d_ws;

    // workspace layout (float offsets)
    float* items   = ws + 0;        // 128000
    float* histemb = ws + 128000;   // 512000
    float* xwm     = ws + 640000;   // 512000
    float* xwd     = ws + 1152000;  // 512000
    float* xwh     = ws + 1664000;  // 2048000
    float* outm    = ws + 3712000;  // 128000
    float* outh    = ws + 3840000;  // 128000
    float* csg     = ws + 3968000;  // 128000
    float* he      = ws + 4096000;  // 512000
    float* pooled  = ws + 4608000;  // 4000
    float* sess    = ws + 4612000;  // 496000
    float* avgd    = ws + 5108000;  // 992
    float* att1    = ws + 5108992;  // 124000
    float* outy    = ws + 5232992;  // 124000
    float* Xbuf    = ws + 5356992;  // 256000

    k_poison<<<dim3(2000), dim3(256), 0, stream>>>(outm, outh, csg, he);
    k_embed<<<dim3(1280), dim3(128), 0, stream>>>(item_vectors, hist_items, emb_W, items, histemb);

    // input-side GEMMs with bias folded in
    k_gemm_bt<<<dim3(32, 4), dim3(256), 0, stream>>>(items, lstm_Wi, lstm_b, xwm, 256, G4_, E_);
    k_gemm_bt<<<dim3(32, 4), dim3(256), 0, stream>>>(items, dil_Wi, dil_b, xwd, 256, G4_, E_);
    k_gemm_bt<<<dim3(32, 16), dim3(256), 0, stream>>>(histemb, hist_Wi, hist_b, xwh, 1024, G4_, E_);

    k_rec10<<<dim3(256), dim3(256), 0, stream>>>(
        xwm, lstm_Wh, xwd, dil_Wh, dilated_idx, xwh, hist_Wh,
        outm, outh, csg, he);

    k_pool<<<dim3(B_), dim3(512), 0, stream>>>(outm, mask, pooled);
    k_sess<<<dim3(B_ * J_ * 31), dim3(512), 0, stream>>>(sequence_tim, item_vectors, hist_tims,
                                                         hist_items, tim_sim, poi_dist, he, sess, avgd);
    k_att1<<<dim3(B_ * 31), dim3(512), 0, stream>>>(sess, pooled, att1);
    k_gemm_bt<<<dim3(8, 4), dim3(256), 0, stream>>>(att1, lin1_W, lin1_b, outy, 248, H_, H_);
    k_att2<<<dim3(B_ * 31), dim3(512), 0, stream>>>(sess, outy, outm, avgd, Xbuf);
    k_mix<<<dim3(B_ * S_), dim3(512), 0, stream>>>(outm, outh, Xbuf);

    k_gemm_bt<<<dim3(79, 4), dim3(256), 0, stream>>>(Xbuf, lin_W, lin_b, out, 256, NI_, 1000);
    k_lsm<<<dim3(256), dim3(512), 0, stream>>>(out);
}

// Round 12
// 1742.194 us; speedup vs baseline: 1.0857x; 1.0857x over previous
//
#include <hip/hip_runtime.h>
#include <hip/hip_bf16.h>
#include <math.h>

// Problem constants
#define B_ 8
#define S_ 32
#define J_ 4
#define L_ 32
#define E_ 500
#define H_ 500
#define NI_ 5000
#define NT_ 48
#define G4_ 2000   // 4*H

// poison bit-pattern: memset byte 0x7F -> float 3.3961514e38. |h|<=1 and
// |c|<=129 can never equal it, so polling "!= poison" is exact.
#define PZBITS_ 0x7F7F7F7Fu

typedef unsigned long long ull;

__device__ __forceinline__ float sigm(float x) { return 1.f / (1.f + expf(-x)); }
__device__ __forceinline__ float seluf(float x) {
    const float sc = 1.0507009873554805f, al = 1.6732632423543772f;
    return x > 0.f ? sc * x : sc * al * (expf(x) - 1.f);
}
// agent-scope ops: bypass L1/L2, coherent at L3; no fences / no wbl2
__device__ __forceinline__ float cohload(const float* p) {
    return __hip_atomic_load(p, __ATOMIC_RELAXED, __HIP_MEMORY_SCOPE_AGENT);
}
__device__ __forceinline__ ull cohload64(const ull* p) {
    return __hip_atomic_load(p, __ATOMIC_RELAXED, __HIP_MEMORY_SCOPE_AGENT);
}
__device__ __forceinline__ void cohstore(float* p, float v) {
    __hip_atomic_store(p, v, __ATOMIC_RELAXED, __HIP_MEMORY_SCOPE_AGENT);
}

// ---------------- merged input-side GEMM with fused embedding gather ----------------
// z=0: xwm = emb[itemv] @ lstm_Wi^T + b   (M=256)
// z=1: xwd = emb[itemv] @ dil_Wi^T  + b   (M=256)
// z=2: xwh = emb[histi] @ hist_Wi^T + b   (M=1024)
#define TBM 64
#define TBN 64
#define TBK 16
__global__ __launch_bounds__(256) void k_gemm_emb(
    const int* __restrict__ itemv, const int* __restrict__ histi,
    const float* __restrict__ embW,
    const float* __restrict__ Wm, const float* __restrict__ bm, float* __restrict__ Cm,
    const float* __restrict__ Wd, const float* __restrict__ bd, float* __restrict__ Cd,
    const float* __restrict__ Wh, const float* __restrict__ bh, float* __restrict__ Ch) {
    const int z = blockIdx.z;
    int M; const int* idx; const float* Bm; const float* bias; float* C;
    if (z == 0)      { M = 256;  idx = itemv; Bm = Wm; bias = bm; C = Cm; }
    else if (z == 1) { M = 256;  idx = itemv; Bm = Wd; bias = bd; C = Cd; }
    else             { M = 1024; idx = histi; Bm = Wh; bias = bh; C = Ch; }
    const int row0 = blockIdx.y * TBM;
    if (row0 >= M) return;
    const int col0 = blockIdx.x * TBN;
    const int K = E_, N = G4_;

    __shared__ float As[TBK][TBM + 1];
    __shared__ float Bs[TBK][TBN + 1];
    const int tid = threadIdx.x;
    const int tx = tid & 15, ty = tid >> 4;
    float acc[4][4] = {};
    for (int k0 = 0; k0 < K; k0 += TBK) {
#pragma unroll
        for (int i = 0; i < 4; ++i) {
            int e = tid + i * 256;
            int kk = e & 15, m = e >> 4;
            int gk = k0 + kk;
            float va = 0.f, vb = 0.f;
            int gm = row0 + m, gn = col0 + m;
            if (gk < K) {
                if (gm < M) va = embW[(size_t)idx[gm] * E_ + gk];
                if (gn < N) vb = Bm[(size_t)gn * K + gk];
            }
            As[kk][m] = va;
            Bs[kk][m] = vb;
        }
        __syncthreads();
#pragma unroll
        for (int kk = 0; kk < TBK; ++kk) {
            float a[4], bb[4];
#pragma unroll
            for (int i = 0; i < 4; ++i) a[i] = As[kk][ty * 4 + i];
#pragma unroll
            for (int i = 0; i < 4; ++i) bb[i] = Bs[kk][tx * 4 + i];
#pragma unroll
            for (int i = 0; i < 4; ++i)
#pragma unroll
                for (int j = 0; j < 4; ++j) acc[i][j] += a[i] * bb[j];
        }
        __syncthreads();
    }
#pragma unroll
    for (int i = 0; i < 4; ++i) {
        int gm = row0 + ty * 4 + i;
        if (gm >= M) continue;
#pragma unroll
        for (int j = 0; j < 4; ++j) {
            int gn = col0 + tx * 4 + j;
            if (gn < N) C[(size_t)gm * N + gn] = acc[i][j] + bias[gn];
        }
    }
}

// ---------------- generic GEMM: C[M,N] = A[M,K] @ B[N,K]^T + bias[N] ----------------
__global__ __launch_bounds__(256) void k_gemm_bt(const float* __restrict__ A,
                                                 const float* __restrict__ Bm,
                                                 const float* __restrict__ bias,
                                                 float* __restrict__ C,
                                                 int M, int N, int K) {
    __shared__ float As[TBK][TBM + 1];
    __shared__ float Bs[TBK][TBN + 1];
    const int tid = threadIdx.x;
    const int tx = tid & 15, ty = tid >> 4;
    const int row0 = blockIdx.y * TBM, col0 = blockIdx.x * TBN;
    float acc[4][4] = {};
    for (int k0 = 0; k0 < K; k0 += TBK) {
#pragma unroll
        for (int i = 0; i < 4; ++i) {
            int e = tid + i * 256;
            int kk = e & 15, m = e >> 4;
            int gk = k0 + kk;
            float va = 0.f, vb = 0.f;
            int gm = row0 + m, gn = col0 + m;
            if (gk < K) {
                if (gm < M) va = A[(size_t)gm * K + gk];
                if (gn < N) vb = Bm[(size_t)gn * K + gk];
            }
            As[kk][m] = va;
            Bs[kk][m] = vb;
        }
        __syncthreads();
#pragma unroll
        for (int kk = 0; kk < TBK; ++kk) {
            float a[4], bb[4];
#pragma unroll
            for (int i = 0; i < 4; ++i) a[i] = As[kk][ty * 4 + i];
#pragma unroll
            for (int i = 0; i < 4; ++i) bb[i] = Bs[kk][tx * 4 + i];
#pragma unroll
            for (int i = 0; i < 4; ++i)
#pragma unroll
                for (int j = 0; j < 4; ++j) acc[i][j] += a[i] * bb[j];
        }
        __syncthreads();
    }
#pragma unroll
    for (int i = 0; i < 4; ++i) {
        int gm = row0 + ty * 4 + i;
        if (gm >= M) continue;
#pragma unroll
        for (int j = 0; j < 4; ++j) {
            int gn = col0 + tx * 4 + j;
            if (gn < N) C[(size_t)gm * N + gn] = acc[i][j] + (bias ? bias[gn] : 0.f);
        }
    }
}

// ---------------- per-batch gang recurrent kernel (v12 = verified v10) ----------------
// 24 independent per-(role,batch) gangs, 256 blocks, poll-on-data with
// memset-poisoned exchange buffers (0x7F bytes). Consumers spin on their own
// 16B chunk via agent-scope loads until all 4 words != poison. Producers
// store h/c agent-scope (write-through to L3). No flags, no gang barrier.
__global__ __launch_bounds__(256) void k_rec12(
    const float* __restrict__ xwm, const float* __restrict__ Whm,
    const float* __restrict__ xwd, const float* __restrict__ Whd,
    const int* __restrict__ dilidx,
    const float* __restrict__ xwh, const float* __restrict__ Whh,
    float* __restrict__ outm, float* __restrict__ outh,
    float* __restrict__ csg, float* __restrict__ he) {
    __shared__ __align__(16) float4 h_s4[125];
    __shared__ float z_s[256];
    const int tid = threadIdx.x;
    const int bid = blockIdx.x;
    const int x = bid & 7, ii = bid >> 3;   // x ~ XCD slot (perf heuristic only)
    int role, b, blk;
    if (x < 4)      { role = 2; b = x * 2 + (ii >> 4);       blk = ii & 15; }
    else if (x < 6) { role = 0; b = (x - 4) * 4 + (ii >> 3); blk = ii & 7;  }
    else            { role = 1; b = (x - 6) * 4 + (ii >> 3); blk = ii & 7;  }

    const int hpbb   = (role == 2) ? 32 : 63;
    const int r0     = blk * hpbb;
    const int hpb    = min(hpbb, 500 - r0);
    const int C      = 4 * hpb;
    const int nsteps = (role == 2) ? 128 : 32;

    const float* Wh = (role == 0) ? Whm : (role == 1) ? Whd : Whh;
    const float* xw = (role == 0) ? xwm : (role == 1) ? xwd : xwh;

    int colg = 0;
    if (tid < C) {
        int gate = tid / hpb;
        int ri = tid - gate * hpb;
        colg = gate * 500 + r0 + ri;
    }
    const float4* wp4 = (const float4*)(Wh + (size_t)colg * 500);

    float c_reg = 0.f;

    for (int t = 0; t < nsteps; ++t) {
        // xw prefetch (independent of h) -> issue first
        float acc = 0.f;
        if (tid < C) acc = xw[((size_t)(b * nsteps + t)) * G4_ + colg];

        float pc_r = 0.f;
        if (t > 0) {
            // ---- stage this batch's h row: poll own 16B chunk until real ----
            const float* hrow;
            if (role == 0)      hrow = outm + ((size_t)(b * S_ + (t - 1))) * H_;
            else if (role == 2) hrow = he + ((size_t)(b * 128 + (t - 1))) * H_;
            else { int it = dilidx[b * S_ + t];
                   hrow = outh + ((size_t)(b * S_ + it)) * H_; }
            if (tid < 125) {
                const ull* p = (const ull*)(hrow + tid * 4);
                union { ull u[2]; float4 f; unsigned us[4]; } uf;
                while (true) {
                    uf.u[0] = cohload64(p);
                    uf.u[1] = cohload64(p + 1);
                    if (uf.us[0] != PZBITS_ && uf.us[1] != PZBITS_ &&
                        uf.us[2] != PZBITS_ && uf.us[3] != PZBITS_) break;
                    __builtin_amdgcn_s_sleep(1);
                }
                h_s4[tid] = uf.f;
            }
            // role-1 prev-cell: poll csg (own h-range) until real
            if (role == 1 && tid < hpb) {
                int it = dilidx[b * S_ + t];
                const float* pp = &csg[((size_t)(b * S_ + it)) * H_ + r0 + tid];
                do { pc_r = cohload(pp); } while (__float_as_uint(pc_r) == PZBITS_);
            }
            __syncthreads();

            // ---- GEMV: dot(h, W[colg]); h reads are LDS broadcasts ----
            if (tid < C) {
                float s0 = 0.f, s1 = 0.f, s2 = 0.f, s3 = 0.f;
#pragma unroll 2
                for (int k4 = 0; k4 < 124; k4 += 4) {
                    float4 w0 = wp4[k4],     h0 = h_s4[k4];
                    float4 w1 = wp4[k4 + 1], h1 = h_s4[k4 + 1];
                    float4 w2 = wp4[k4 + 2], h2 = h_s4[k4 + 2];
                    float4 w3 = wp4[k4 + 3], h3 = h_s4[k4 + 3];
                    s0 += w0.x * h0.x + w0.y * h0.y + w0.z * h0.z + w0.w * h0.w;
                    s1 += w1.x * h1.x + w1.y * h1.y + w1.z * h1.z + w1.w * h1.w;
                    s2 += w2.x * h2.x + w2.y * h2.y + w2.z * h2.z + w2.w * h2.w;
                    s3 += w3.x * h3.x + w3.y * h3.y + w3.z * h3.z + w3.w * h3.w;
                }
                float4 wt = wp4[124], ht = h_s4[124];
                s0 += wt.x * ht.x + wt.y * ht.y + wt.z * ht.z + wt.w * ht.w;
                acc += (s0 + s1) + (s2 + s3);
            }
        }
        z_s[tid] = acc;
        __syncthreads();

        // ---- gate update for this block's hpb h-indices ----
        if (tid < hpb) {
            float zi = z_s[tid];
            float zf = z_s[tid + hpb];
            float zg = z_s[tid + 2 * hpb];
            float zo = z_s[tid + 3 * hpb];
            float pc = (role == 1) ? pc_r : c_reg;
            float cc = sigm(zf) * pc + sigm(zi) * tanhf(zg);
            float hh = sigm(zo) * tanhf(cc);
            c_reg = cc;
            int r = r0 + tid;
            if (role == 0) {
                cohstore(&outm[((size_t)(b * S_ + t)) * H_ + r], hh);
            } else if (role == 2) {
                cohstore(&he[((size_t)(b * 128 + t)) * H_ + r], hh);
            } else {
                cohstore(&outh[((size_t)(b * S_ + t)) * H_ + r], hh);
                cohstore(&csg[((size_t)(b * S_ + t)) * H_ + r], cc);
            }
        }
        __syncthreads();   // protects z_s/h_s reuse next iteration
    }
}

// ---------------- masked mean pooling ----------------
__global__ __launch_bounds__(512) void k_pool(const float* __restrict__ outm,
                                              const float* __restrict__ mask,
                                              float* __restrict__ pooled) {
    int b = blockIdx.x, tid = threadIdx.x;
    if (tid >= 500) return;
    float acc = 0.f, den = 0.f;
    for (int s = 0; s < S_; ++s) {
        float mk = mask[b * S_ + s];
        acc += outm[((size_t)(b * S_ + s)) * H_ + tid] * mk;
        den += mk;
    }
    pooled[b * H_ + tid] = acc / den;
}

// ---------------- session rep: sess[b,j,s,:] and avgd[b,j,s] ----------------
__global__ __launch_bounds__(512) void k_sess(const int* __restrict__ seqtim,
                                              const int* __restrict__ itemv,
                                              const int* __restrict__ histt,
                                              const int* __restrict__ histi,
                                              const float* __restrict__ timsim,
                                              const float* __restrict__ poid,
                                              const float* __restrict__ he,
                                              float* __restrict__ sess,
                                              float* __restrict__ avgd) {
    int bi = blockIdx.x;                // B*J*31
    int s = bi % 31;
    int tmpv = bi / 31;
    int j = tmpv & 3, b = tmpv >> 2;
    __shared__ float w[L_];
    __shared__ float pd[L_];
    __shared__ float stats[1];
    int tid = threadIdx.x;
    int st = seqtim[b * S_ + s];
    if (tid < L_) {
        int ht = histt[(b * J_ + j) * L_ + tid];
        w[tid] = timsim[st * NT_ + ht];
    }
    if (tid >= 64 && tid < 64 + L_) {   // parallel poi_dist gather
        int l = tid - 64;
        int iv = itemv[b * S_ + s];
        pd[l] = poid[(size_t)iv * NI_ + histi[(b * J_ + j) * L_ + l]];
    }
    __syncthreads();
    if (tid == 64) {
        float a = 0.f;
        for (int l = 0; l < L_; ++l) a += pd[l];
        avgd[(b * J_ + j) * 31 + s] = a * (1.f / 32.f);
    }
    if (tid == 0) {
        float m = -1e30f;
        for (int l = 0; l < L_; ++l) m = fmaxf(m, w[l]);
        float sm = 0.f;
        for (int l = 0; l < L_; ++l) { float e = expf(w[l] - m); w[l] = e; sm += e; }
        stats[0] = 1.f / sm;
    }
    __syncthreads();
    if (tid < 500) {
        float inv = stats[0];
        float acc = 0.f;
        const float* hp = he + ((size_t)(b * J_ * L_ + j * L_)) * H_ + tid;
        for (int l = 0; l < L_; ++l) acc += w[l] * inv * hp[(size_t)l * H_];
        sess[((size_t)((b * J_ + j) * 31 + s)) * H_ + tid] = acc;
    }
}

// ---------------- attention 1 ----------------
__global__ __launch_bounds__(512) void k_att1(const float* __restrict__ sess,
                                              const float* __restrict__ pooled,
                                              float* __restrict__ att1) {
    int bi = blockIdx.x;   // B*31
    int s = bi % 31, b = bi / 31;
    __shared__ float vec[H_];
    __shared__ float part[512];
    int tid = threadIdx.x;
    if (tid < 500) vec[tid] = pooled[b * H_ + tid];
    __syncthreads();
    int j = tid >> 7, i = tid & 127;
    const float* sp = sess + ((size_t)((b * J_ + j) * 31 + s)) * H_;
    float acc = 0.f;
    for (int h = i; h < H_; h += 128) acc += sp[h] * vec[h];
    part[tid] = acc;
    __syncthreads();
    for (int off = 64; off > 0; off >>= 1) {
        if (i < off) part[tid] += part[tid + off];
        __syncthreads();
    }
    float d0 = part[0], d1 = part[128], d2 = part[256], d3 = part[384];
    float m = fmaxf(fmaxf(d0, d1), fmaxf(d2, d3));
    float e0 = expf(d0 - m), e1 = expf(d1 - m), e2 = expf(d2 - m), e3 = expf(d3 - m);
    float inv = 1.f / (e0 + e1 + e2 + e3);
    if (tid < 500) {
        const float* s0 = sess + ((size_t)(b * J_ * 31 + s)) * H_ + tid;
        const size_t js = (size_t)31 * H_;
        float r = e0 * inv * s0[0] + e1 * inv * s0[js] + e2 * inv * s0[2 * js] + e3 * inv * s0[3 * js];
        att1[((size_t)(b * 31 + s)) * H_ + tid] = r;
    }
}

// ---------------- attention 2 + mix (fused; grid B*32) ----------------
__global__ __launch_bounds__(512) void k_att2m(const float* __restrict__ sess,
                                               const float* __restrict__ outy,
                                               const float* __restrict__ outm,
                                               const float* __restrict__ outh,
                                               const float* __restrict__ avgd,
                                               float* __restrict__ X) {
    int bi = blockIdx.x;   // B*32
    int s = bi & 31, b = bi >> 5;
    int tid = threadIdx.x;
    __shared__ float vec[H_];
    __shared__ float part[512];

    // mix half: X[:, 500:1000] = 0.5*(selu(out)+selu(out_hie))  (all s)
    if (tid < 500) {
        size_t idx = (size_t)(b * S_ + s) * H_ + tid;
        X[(size_t)(b * S_ + s) * 1000 + 500 + tid] =
            0.5f * (seluf(outm[idx]) + seluf(outh[idx]));
    }
    if (s == 31) {   // y padded row
        if (tid < 500) X[(size_t)(b * S_ + s) * 1000 + tid] = 0.f;
        return;
    }

    if (tid < 500)
        vec[tid] = 0.5f * seluf(outy[((size_t)(b * 31 + s)) * H_ + tid]) +
                   0.5f * outm[((size_t)(b * S_ + s)) * H_ + tid];
    __syncthreads();
    int j = tid >> 7, i = tid & 127;
    const float* sp = sess + ((size_t)((b * J_ + j) * 31 + s)) * H_;
    float acc = 0.f;
    for (int h = i; h < H_; h += 128) acc += sp[h] * vec[h];
    part[tid] = acc;
    __syncthreads();
    for (int off = 64; off > 0; off >>= 1) {
        if (i < off) part[tid] += part[tid + off];
        __syncthreads();
    }
    float d0 = part[0]   / avgd[(b * J_ + 0) * 31 + s];
    float d1 = part[128] / avgd[(b * J_ + 1) * 31 + s];
    float d2 = part[256] / avgd[(b * J_ + 2) * 31 + s];
    float d3 = part[384] / avgd[(b * J_ + 3) * 31 + s];
    float m = fmaxf(fmaxf(d0, d1), fmaxf(d2, d3));
    float e0 = expf(d0 - m), e1 = expf(d1 - m), e2 = expf(d2 - m), e3 = expf(d3 - m);
    float inv = 1.f / (e0 + e1 + e2 + e3);
    if (tid < 500) {
        const float* s0 = sess + ((size_t)(b * J_ * 31 + s)) * H_ + tid;
        const size_t js = (size_t)31 * H_;
        float r = e0 * inv * s0[0] + e1 * inv * s0[js] + e2 * inv * s0[2 * js] + e3 * inv * s0[3 * js];
        X[((size_t)(b * S_ + s)) * 1000 + tid] = seluf(r);
    }
}

// ---------------- in-place log_softmax over rows of 5000 ----------------
__global__ __launch_bounds__(512) void k_lsm(float* __restrict__ out) {
    int row = blockIdx.x, tid = threadIdx.x;
    float* p = out + (size_t)row * NI_;
    __shared__ float red[512];
    float m = -1e30f;
    for (int i = tid; i < NI_; i += 512) m = fmaxf(m, p[i]);
    red[tid] = m;
    __syncthreads();
    for (int off = 256; off > 0; off >>= 1) {
        if (tid < off) red[tid] = fmaxf(red[tid], red[tid + off]);
        __syncthreads();
    }
    m = red[0];
    __syncthreads();
    float sm = 0.f;
    for (int i = tid; i < NI_; i += 512) sm += expf(p[i] - m);
    red[tid] = sm;
    __syncthreads();
    for (int off = 256; off > 0; off >>= 1) {
        if (tid < off) red[tid] += red[tid + off];
        __syncthreads();
    }
    float lse = m + logf(red[0]);
    __syncthreads();
    for (int i = tid; i < NI_; i += 512) p[i] -= lse;
}

extern "C" void kernel_launch(void* const* d_in, const int* in_sizes, int n_in,
                              void* d_out, int out_size, void* d_ws, size_t ws_size,
                              hipStream_t stream) {
    const int* item_vectors = (const int*)d_in[0];
    const int* sequence_tim = (const int*)d_in[1];
    const int* dilated_idx  = (const int*)d_in[2];
    const int* hist_items   = (const int*)d_in[3];
    const int* hist_tims    = (const int*)d_in[4];
    const float* mask       = (const float*)d_in[5];
    const float* tim_sim    = (const float*)d_in[6];
    const float* poi_dist   = (const float*)d_in[7];
    const float* emb_W      = (const float*)d_in[8];
    const float* lstm_Wi    = (const float*)d_in[9];
    const float* lstm_Wh    = (const float*)d_in[10];
    const float* lstm_b     = (const float*)d_in[11];
    const float* hist_Wi    = (const float*)d_in[12];
    const float* hist_Wh    = (const float*)d_in[13];
    const float* hist_b     = (const float*)d_in[14];
    const float* dil_Wi     = (const float*)d_in[15];
    const float* dil_Wh     = (const float*)d_in[16];
    const float* dil_b      = (const float*)d_in[17];
    const float* lin1_W     = (const float*)d_in[18];
    const float* lin1_b     = (const float*)d_in[19];
    const float* lin_W      = (const float*)d_in[20];
    const float* lin_b      = (const float*)d_in[21];
    float* out = (float*)d_out;
    float* ws  = (float*)d_ws;

    // workspace layout (float offsets)
    float* xwm     = ws + 640000;   // 512000
    float* xwd     = ws + 1152000;  // 512000
    float* xwh     = ws + 1664000;  // 2048000
    float* outm    = ws + 3712000;  // 128000  ─┐ contiguous poison range
    float* outh    = ws + 3840000;  // 128000   │ (896000 floats)
    float* csg     = ws + 3968000;  // 128000   │
    float* he      = ws + 4096000;  // 512000  ─┘
    float* pooled  = ws + 4608000;  // 4000
    float* sess    = ws + 4612000;  // 496000
    float* avgd    = ws + 5108000;  // 992
    float* att1    = ws + 5108992;  // 124000
    float* outy    = ws + 5232992;  // 124000
    float* Xbuf    = ws + 5356992;  // 256000

    // poison the exchange buffers with 0x7F bytes (one async memset, graph-safe)
    hipMemsetAsync((void*)outm, 0x7F, (size_t)896000 * sizeof(float), stream);

    // merged input-side GEMMs with fused embedding gather + bias
    k_gemm_emb<<<dim3(32, 16, 3), dim3(256), 0, stream>>>(
        item_vectors, hist_items, emb_W,
        lstm_Wi, lstm_b, xwm,
        dil_Wi,  dil_b,  xwd,
        hist_Wi, hist_b, xwh);

    k_rec12<<<dim3(256), dim3(256), 0, stream>>>(
        xwm, lstm_Wh, xwd, dil_Wh, dilated_idx, xwh, hist_Wh,
        outm, outh, csg, he);

    k_pool<<<dim3(B_), dim3(512), 0, stream>>>(outm, mask, pooled);
    k_sess<<<dim3(B_ * J_ * 31), dim3(512), 0, stream>>>(sequence_tim, item_vectors, hist_tims,
                                                         hist_items, tim_sim, poi_dist, he, sess, avgd);
    k_att1<<<dim3(B_ * 31), dim3(512), 0, stream>>>(sess, pooled, att1);
    k_gemm_bt<<<dim3(8, 4), dim3(256), 0, stream>>>(att1, lin1_W, lin1_b, outy, 248, H_, H_);
    k_att2m<<<dim3(B_ * 32), dim3(512), 0, stream>>>(sess, outy, outm, outh, avgd, Xbuf);

    k_gemm_bt<<<dim3(79, 4), dim3(256), 0, stream>>>(Xbuf, lin_W, lin_b, out, 256, NI_, 1000);
    k_lsm<<<dim3(256), dim3(512), 0, stream>>>(out);
}